// Round 1
// baseline (223.244 us; speedup 1.0000x reference)
//
#include <hip/hip_runtime.h>

// GroupConv2D: NHWC, B=32, H=W=56, Cin=Cout=256, groups=8 (32 ch/group), 3x3 SAME.
// Implicit-GEMM per group: M=pixels, N=32(co), K=288 (9 taps x 32 ci).
// mfma_f32_16x16x32_bf16: one K-step == one (ky,kx) tap, 8 contiguous ci per lane
// -> A-fragments are straight ds_read_b128 from an NHWC bf16 LDS tile (no im2col).
// Block = 256 thr = 4 waves: one (batch, group, 8-row strip) = 448 px x 32 co.
//   LDS: input halo tile 10x58x32 bf16 (37 KB) + weights [tap][co][ci] (18 KB) = 55.5 KB
//   -> 2 blocks/CU. Grid = 7x8x32 = 1792 blocks (7 per CU).
// Memory-bound target: ~206 MB @ 6.3 TB/s ~= 33 us.

#define R_ 8                 // output rows per block
#define TPW 7                // 16-pixel tiles per wave (28 tiles / 4 waves)

typedef __bf16 bf16x8 __attribute__((ext_vector_type(8)));
typedef float floatx4 __attribute__((ext_vector_type(4)));
typedef unsigned short ushortx4 __attribute__((ext_vector_type(4)));

__device__ __forceinline__ unsigned short f2bf(float f) {
    unsigned int u = __builtin_bit_cast(unsigned int, f);
    u += 0x7fffu + ((u >> 16) & 1u);           // round-to-nearest-even
    return (unsigned short)(u >> 16);
}

__global__ __launch_bounds__(256, 2)
void gconv_mfma(const float* __restrict__ in, const float* __restrict__ wgt,
                const float* __restrict__ bias, float* __restrict__ out) {
    const int rt = blockIdx.x;      // 0..6 row-strip
    const int g  = blockIdx.y;      // 0..7 group
    const int b  = blockIdx.z;      // 0..31 batch
    const int y0 = rt * R_;

    __shared__ unsigned short lds_in[10 * 58 * 32];   // [row][col][ci] bf16, 37120 B
    __shared__ unsigned short lds_w[9 * 32 * 32];     // [tap][co][ci]  bf16, 18432 B

    const int tid = threadIdx.x;

    // ---- stage weights: global [tap][ci][256] (slice g) -> LDS [tap][co][ci]
    for (int i = tid; i < 9 * 32 * 32; i += 256) {
        const int co = i & 31;
        const int ci = (i >> 5) & 31;
        const int kk = i >> 10;
        lds_w[(kk * 32 + co) * 32 + ci] = f2bf(wgt[(kk * 32 + ci) * 256 + g * 32 + co]);
    }

    // ---- stage input halo tile: rows y0-1..y0+8 (10), cols -1..56 (58), 32 ci
    // one chunk = 4 consecutive ci (float4 load -> 8B LDS write), 4640 chunks
    for (int c = tid; c < 10 * 58 * 8; c += 256) {
        const int row = c / 464;            // 58*8
        const int rem = c - row * 464;
        const int col = rem >> 3;
        const int q   = rem & 7;
        const int gy = y0 - 1 + row;
        const int gx = col - 1;
        float4 v = make_float4(0.f, 0.f, 0.f, 0.f);
        if ((unsigned)gy < 56u && (unsigned)gx < 56u) {
            v = *reinterpret_cast<const float4*>(
                &in[(((b * 56 + gy) * 56 + gx) * 256) + g * 32 + q * 4]);
        }
        ushortx4 p;
        p.x = f2bf(v.x); p.y = f2bf(v.y); p.z = f2bf(v.z); p.w = f2bf(v.w);
        *reinterpret_cast<ushortx4*>(&lds_in[(row * 58 + col) * 32 + q * 4]) = p;
    }

    __syncthreads();

    const int wv   = tid >> 6;
    const int lane = tid & 63;
    const int lc   = lane & 15;    // A: m-index; B: n-index; C/D: col
    const int quad = lane >> 4;

    // per-lane A base address (ushort units) for each of this wave's 7 pixel tiles
    int lane_base[TPW];
#pragma unroll
    for (int t = 0; t < TPW; ++t) {
        const int p  = (wv * TPW + t) * 16 + lc;     // output pixel 0..447 in strip
        const int yl = p / 56;
        const int xl = p - yl * 56;
        lane_base[t] = (yl * 58 + xl) * 32 + quad * 8;
    }

    floatx4 acc[TPW][2];
#pragma unroll
    for (int t = 0; t < TPW; ++t) {
        acc[t][0] = (floatx4)(0.f);
        acc[t][1] = (floatx4)(0.f);
    }

#pragma unroll
    for (int kk = 0; kk < 9; ++kk) {
        const int ky = kk / 3, kx = kk % 3;
        const int koff = (ky * 58 + kx) * 32;        // wave-uniform tap offset
        // B fragments: B[k=quad*8+j][n=lc(+16)] == lds_w[kk][co][quad*8..+7]
        const bf16x8 bf0 = *reinterpret_cast<const bf16x8*>(
            &lds_w[(kk * 32 + lc) * 32 + quad * 8]);
        const bf16x8 bf1 = *reinterpret_cast<const bf16x8*>(
            &lds_w[(kk * 32 + 16 + lc) * 32 + quad * 8]);
#pragma unroll
        for (int t = 0; t < TPW; ++t) {
            const bf16x8 a = *reinterpret_cast<const bf16x8*>(&lds_in[lane_base[t] + koff]);
            acc[t][0] = __builtin_amdgcn_mfma_f32_16x16x32_bf16(a, bf0, acc[t][0], 0, 0, 0);
            acc[t][1] = __builtin_amdgcn_mfma_f32_16x16x32_bf16(a, bf1, acc[t][1], 0, 0, 0);
        }
    }

    // ---- epilogue: C/D layout col=lc (co), row=quad*4+r (pixel); add bias, store fp32
    const float bv0 = bias[g * 32 + lc];
    const float bv1 = bias[g * 32 + 16 + lc];
#pragma unroll
    for (int t = 0; t < TPW; ++t) {
#pragma unroll
        for (int r = 0; r < 4; ++r) {
            const int p = (wv * TPW + t) * 16 + quad * 4 + r;
            const int y = p / 56;
            const int x = p - y * 56;
            float* o = &out[(((b * 56) + y0 + y) * 56 + x) * 256 + g * 32];
            o[lc]      = acc[t][0][r] + bv0;
            o[16 + lc] = acc[t][1][r] + bv1;
        }
    }
}

extern "C" void kernel_launch(void* const* d_in, const int* in_sizes, int n_in,
                              void* d_out, int out_size, void* d_ws, size_t ws_size,
                              hipStream_t stream) {
    const float* in   = (const float*)d_in[0];
    const float* wgt  = (const float*)d_in[1];
    const float* bias = (const float*)d_in[2];
    float* out        = (float*)d_out;
    dim3 grid(7, 8, 32);   // (row-strips, groups, batch)
    gconv_mfma<<<grid, dim3(256, 1, 1), 0, stream>>>(in, wgt, bias, out);
}

// Round 2
// 197.577 us; speedup vs baseline: 1.1299x; 1.1299x over previous
//
#include <hip/hip_runtime.h>

// GroupConv2D: NHWC, B=32, H=W=56, Cin=Cout=256, groups=8 (32 ch/group), 3x3 SAME.
// Implicit-GEMM per group: M=pixels, N=32(co), K=288 (9 taps x 32 ci).
// mfma_f32_16x16x32_bf16: one K-step == one (ky,kx) tap, 8 contiguous ci per lane.
//
// R2 change vs R1 (101 us, Occ 19%, MfmaUtil 5.5%, VALU 15% -- latency-bound):
//  - weights no longer staged in LDS per block (was 18 KB + 9216 scalar loads/block).
//    A prep kernel converts/transposes them ONCE per launch into d_ws as bf16
//    [g][tap][co][ci]; main kernel loads B-fragments as single 16B dwordx4 (L2-hot).
//  - LDS drops 55.8 -> 37.1 KB  => 4 blocks/CU (was 2), launch_bounds(256,4).
// Target: ~50 us (HBM floor ~30 us at 169 MB observed traffic).

#define R_ 8                 // output rows per block
#define TPW 7                // 16-pixel tiles per wave (28 tiles / 4 waves)

typedef __bf16 bf16x8 __attribute__((ext_vector_type(8)));
typedef float floatx4 __attribute__((ext_vector_type(4)));
typedef unsigned short ushortx4 __attribute__((ext_vector_type(4)));

__device__ __forceinline__ unsigned short f2bf(float f) {
    unsigned int u = __builtin_bit_cast(unsigned int, f);
    u += 0x7fffu + ((u >> 16) & 1u);           // round-to-nearest-even
    return (unsigned short)(u >> 16);
}

// ---- prep: wgt fp32 [tap][ci][co256] -> ws bf16 [g][tap][co][ci]  (73728 elems)
__global__ __launch_bounds__(256)
void wprep(const float* __restrict__ wgt, unsigned short* __restrict__ wbf) {
    const int i = blockIdx.x * 256 + threadIdx.x;       // grid sized exactly
    const int co256 = i & 255;
    const int tmp   = i >> 8;
    const int ci    = tmp & 31;
    const int kk    = tmp >> 5;                          // 0..8
    const int g  = co256 >> 5;
    const int co = co256 & 31;
    wbf[((g * 9 + kk) * 32 + co) * 32 + ci] = f2bf(wgt[i]);
}

__global__ __launch_bounds__(256, 4)
void gconv_mfma(const float* __restrict__ in, const unsigned short* __restrict__ wbf,
                const float* __restrict__ bias, float* __restrict__ out) {
    const int rt = blockIdx.x;      // 0..6 row-strip
    const int g  = blockIdx.y;      // 0..7 group
    const int b  = blockIdx.z;      // 0..31 batch
    const int y0 = rt * R_;

    __shared__ unsigned short lds_in[10 * 58 * 32];   // [row][col][ci] bf16, 37120 B

    const int tid = threadIdx.x;

    // ---- stage input halo tile: rows y0-1..y0+8 (10), cols -1..56 (58), 32 ci
    // one chunk = 4 consecutive ci (float4 load -> 8B LDS write), 4640 chunks
    for (int c = tid; c < 10 * 58 * 8; c += 256) {
        const int row = c / 464;            // 58*8
        const int rem = c - row * 464;
        const int col = rem >> 3;
        const int q   = rem & 7;
        const int gy = y0 - 1 + row;
        const int gx = col - 1;
        float4 v = make_float4(0.f, 0.f, 0.f, 0.f);
        if ((unsigned)gy < 56u && (unsigned)gx < 56u) {
            v = *reinterpret_cast<const float4*>(
                &in[(((b * 56 + gy) * 56 + gx) * 256) + g * 32 + q * 4]);
        }
        ushortx4 p;
        p.x = f2bf(v.x); p.y = f2bf(v.y); p.z = f2bf(v.z); p.w = f2bf(v.w);
        *reinterpret_cast<ushortx4*>(&lds_in[(row * 58 + col) * 32 + q * 4]) = p;
    }

    __syncthreads();

    const int wv   = tid >> 6;
    const int lane = tid & 63;
    const int lc   = lane & 15;    // A: m-index; B: n-index; C/D: col
    const int quad = lane >> 4;

    // per-lane A base address (ushort units) for each of this wave's 7 pixel tiles
    int lane_base[TPW];
#pragma unroll
    for (int t = 0; t < TPW; ++t) {
        const int p  = (wv * TPW + t) * 16 + lc;     // output pixel 0..447 in strip
        const int yl = p / 56;
        const int xl = p - yl * 56;
        lane_base[t] = (yl * 58 + xl) * 32 + quad * 8;
    }

    // B-fragment base in ws: [g][kk][co][ci] bf16; lane (lc,quad) reads 8 contiguous ci
    const unsigned short* wq = &wbf[((g * 9) * 32) * 32 + quad * 8];  // + (kk*32+co)*32

    floatx4 acc[TPW][2];
#pragma unroll
    for (int t = 0; t < TPW; ++t) {
        acc[t][0] = (floatx4)(0.f);
        acc[t][1] = (floatx4)(0.f);
    }

    // prefetch tap 0's B-fragments
    bf16x8 b0 = *reinterpret_cast<const bf16x8*>(&wq[(0 * 32 + lc) * 32]);
    bf16x8 b1 = *reinterpret_cast<const bf16x8*>(&wq[(0 * 32 + 16 + lc) * 32]);

#pragma unroll
    for (int kk = 0; kk < 9; ++kk) {
        const int ky = kk / 3, kx = kk % 3;
        const int koff = (ky * 58 + kx) * 32;        // wave-uniform tap offset
        bf16x8 nb0 = b0, nb1 = b1;
        if (kk < 8) {   // prefetch next tap (L2-hot) while MFMAs run
            nb0 = *reinterpret_cast<const bf16x8*>(&wq[((kk + 1) * 32 + lc) * 32]);
            nb1 = *reinterpret_cast<const bf16x8*>(&wq[((kk + 1) * 32 + 16 + lc) * 32]);
        }
#pragma unroll
        for (int t = 0; t < TPW; ++t) {
            const bf16x8 a = *reinterpret_cast<const bf16x8*>(&lds_in[lane_base[t] + koff]);
            acc[t][0] = __builtin_amdgcn_mfma_f32_16x16x32_bf16(a, b0, acc[t][0], 0, 0, 0);
            acc[t][1] = __builtin_amdgcn_mfma_f32_16x16x32_bf16(a, b1, acc[t][1], 0, 0, 0);
        }
        b0 = nb0; b1 = nb1;
    }

    // ---- epilogue: C/D layout col=lc (co), row=quad*4+r (pixel); add bias, store fp32
    const float bv0 = bias[g * 32 + lc];
    const float bv1 = bias[g * 32 + 16 + lc];
#pragma unroll
    for (int t = 0; t < TPW; ++t) {
#pragma unroll
        for (int r = 0; r < 4; ++r) {
            const int p = (wv * TPW + t) * 16 + quad * 4 + r;
            const int y = p / 56;
            const int x = p - y * 56;
            float* o = &out[(((b * 56) + y0 + y) * 56 + x) * 256 + g * 32];
            o[lc]      = acc[t][0][r] + bv0;
            o[16 + lc] = acc[t][1][r] + bv1;
        }
    }
}

// ---------------- fallback (round-1 kernel, known correct) if ws too small ----
__global__ __launch_bounds__(256, 2)
void gconv_mfma_ldsw(const float* __restrict__ in, const float* __restrict__ wgt,
                     const float* __restrict__ bias, float* __restrict__ out) {
    const int rt = blockIdx.x, g = blockIdx.y, b = blockIdx.z;
    const int y0 = rt * R_;
    __shared__ unsigned short lds_in[10 * 58 * 32];
    __shared__ unsigned short lds_w[9 * 32 * 32];
    const int tid = threadIdx.x;
    for (int i = tid; i < 9 * 32 * 32; i += 256) {
        const int co = i & 31, ci = (i >> 5) & 31, kk = i >> 10;
        lds_w[(kk * 32 + co) * 32 + ci] = f2bf(wgt[(kk * 32 + ci) * 256 + g * 32 + co]);
    }
    for (int c = tid; c < 10 * 58 * 8; c += 256) {
        const int row = c / 464, rem = c - row * 464, col = rem >> 3, q = rem & 7;
        const int gy = y0 - 1 + row, gx = col - 1;
        float4 v = make_float4(0.f, 0.f, 0.f, 0.f);
        if ((unsigned)gy < 56u && (unsigned)gx < 56u)
            v = *reinterpret_cast<const float4*>(&in[(((b * 56 + gy) * 56 + gx) * 256) + g * 32 + q * 4]);
        ushortx4 p;
        p.x = f2bf(v.x); p.y = f2bf(v.y); p.z = f2bf(v.z); p.w = f2bf(v.w);
        *reinterpret_cast<ushortx4*>(&lds_in[(row * 58 + col) * 32 + q * 4]) = p;
    }
    __syncthreads();
    const int wv = tid >> 6, lane = tid & 63, lc = lane & 15, quad = lane >> 4;
    int lane_base[TPW];
#pragma unroll
    for (int t = 0; t < TPW; ++t) {
        const int p = (wv * TPW + t) * 16 + lc;
        const int yl = p / 56, xl = p - yl * 56;
        lane_base[t] = (yl * 58 + xl) * 32 + quad * 8;
    }
    floatx4 acc[TPW][2];
#pragma unroll
    for (int t = 0; t < TPW; ++t) { acc[t][0] = (floatx4)(0.f); acc[t][1] = (floatx4)(0.f); }
#pragma unroll
    for (int kk = 0; kk < 9; ++kk) {
        const int ky = kk / 3, kx = kk % 3;
        const int koff = (ky * 58 + kx) * 32;
        const bf16x8 bf0 = *reinterpret_cast<const bf16x8*>(&lds_w[(kk * 32 + lc) * 32 + quad * 8]);
        const bf16x8 bf1 = *reinterpret_cast<const bf16x8*>(&lds_w[(kk * 32 + 16 + lc) * 32 + quad * 8]);
#pragma unroll
        for (int t = 0; t < TPW; ++t) {
            const bf16x8 a = *reinterpret_cast<const bf16x8*>(&lds_in[lane_base[t] + koff]);
            acc[t][0] = __builtin_amdgcn_mfma_f32_16x16x32_bf16(a, bf0, acc[t][0], 0, 0, 0);
            acc[t][1] = __builtin_amdgcn_mfma_f32_16x16x32_bf16(a, bf1, acc[t][1], 0, 0, 0);
        }
    }
    const float bv0 = bias[g * 32 + lc], bv1 = bias[g * 32 + 16 + lc];
#pragma unroll
    for (int t = 0; t < TPW; ++t)
#pragma unroll
        for (int r = 0; r < 4; ++r) {
            const int p = (wv * TPW + t) * 16 + quad * 4 + r;
            const int y = p / 56, x = p - y * 56;
            float* o = &out[(((b * 56) + y0 + y) * 56 + x) * 256 + g * 32];
            o[lc] = acc[t][0][r] + bv0;
            o[16 + lc] = acc[t][1][r] + bv1;
        }
}

extern "C" void kernel_launch(void* const* d_in, const int* in_sizes, int n_in,
                              void* d_out, int out_size, void* d_ws, size_t ws_size,
                              hipStream_t stream) {
    const float* in   = (const float*)d_in[0];
    const float* wgt  = (const float*)d_in[1];
    const float* bias = (const float*)d_in[2];
    float* out        = (float*)d_out;
    dim3 grid(7, 8, 32);   // (row-strips, groups, batch)

    if (ws_size >= (size_t)(8 * 9 * 32 * 32 * sizeof(unsigned short))) {
        unsigned short* wbf = (unsigned short*)d_ws;
        wprep<<<dim3(288, 1, 1), dim3(256, 1, 1), 0, stream>>>(wgt, wbf);
        gconv_mfma<<<grid, dim3(256, 1, 1), 0, stream>>>(in, wbf, bias, out);
    } else {
        gconv_mfma_ldsw<<<grid, dim3(256, 1, 1), 0, stream>>>(in, wgt, bias, out);
    }
}